// Round 1
// baseline (459.981 us; speedup 1.0000x reference)
//
#include <hip/hip_runtime.h>
#include <cstddef>

#define HIDDEN    1024
#define OUTD      1024
#define NUM_TABLE 64
#define CODE_LEN  10
#define TABLE_SZ  1024
#define TOTAL_DIM 640

// ---------------- GEMM: z = x @ W + b_proj  (fp32, vector ALU) ----------------
// x [N,1024] row-major, W [1024,640] row-major, z [N,640]
#define BM 64
#define BN 64
#define BK 16

__global__ __launch_bounds__(256)
void gemm_proj(const float* __restrict__ x, const float* __restrict__ W,
               const float* __restrict__ bproj, float* __restrict__ z)
{
    // As transposed: As[k][m], row stride 68 floats (272 B = 17*16 -> float4 aligned)
    __shared__ float As[BK][BM + 4];
    __shared__ float Bs[BK][BN];

    const int tid  = threadIdx.x;
    const int brow = blockIdx.x * BM;
    const int bcol = blockIdx.y * BN;
    const int tr   = tid >> 4;   // 0..15
    const int tc   = tid & 15;   // 0..15

    float acc[4][4] = {};

    for (int k0 = 0; k0 < HIDDEN; k0 += BK) {
        // load A tile (64 rows x 16 cols), store transposed
        #pragma unroll
        for (int i = 0; i < 4; ++i) {
            int idx = tid + i * 256;
            int r = idx >> 4, c = idx & 15;
            As[c][r] = x[(size_t)(brow + r) * HIDDEN + (k0 + c)];
        }
        // load B tile (16 rows x 64 cols)
        #pragma unroll
        for (int i = 0; i < 4; ++i) {
            int idx = tid + i * 256;
            int kk = idx >> 6, m = idx & 63;
            Bs[kk][m] = W[(size_t)(k0 + kk) * TOTAL_DIM + (bcol + m)];
        }
        __syncthreads();

        #pragma unroll
        for (int kk = 0; kk < BK; ++kk) {
            float4 a = *(const float4*)&As[kk][tr * 4];
            float4 b = *(const float4*)&Bs[kk][tc * 4];
            acc[0][0] += a.x * b.x; acc[0][1] += a.x * b.y; acc[0][2] += a.x * b.z; acc[0][3] += a.x * b.w;
            acc[1][0] += a.y * b.x; acc[1][1] += a.y * b.y; acc[1][2] += a.y * b.z; acc[1][3] += a.y * b.w;
            acc[2][0] += a.z * b.x; acc[2][1] += a.z * b.y; acc[2][2] += a.z * b.z; acc[2][3] += a.z * b.w;
            acc[3][0] += a.w * b.x; acc[3][1] += a.w * b.y; acc[3][2] += a.w * b.z; acc[3][3] += a.w * b.w;
        }
        __syncthreads();
    }

    // epilogue: + b_proj, store z
    #pragma unroll
    for (int i = 0; i < 4; ++i) {
        int r = brow + tr * 4 + i;
        #pragma unroll
        for (int j = 0; j < 4; ++j) {
            int c = bcol + tc * 4 + j;
            z[(size_t)r * TOTAL_DIM + c] = acc[i][j] + bproj[c];
        }
    }
}

// ---------------- code / score from z ----------------
__global__ __launch_bounds__(256)
void code_score(const float* __restrict__ z, int* __restrict__ code,
                float* __restrict__ score, int NT)
{
    int idx = blockIdx.x * 256 + threadIdx.x;
    if (idx >= NT) return;
    int n = idx >> 6;        // token
    int t = idx & 63;        // table
    const float* zp = z + (size_t)n * TOTAL_DIM + t * CODE_LEN;
    float s = 1.0f;
    int   c = 0;
    #pragma unroll
    for (int i = 0; i < CODE_LEN; ++i) {
        float v = zp[i];
        s *= 0.5f * (1.0f + tanhf(fabsf(v)));
        c |= (v > 0.0f) ? (1 << i) : 0;
    }
    code[idx]  = c;
    score[idx] = s;
}

// ---------------- gather + weighted sum ----------------
// one block per token; 256 threads x float4 = 1024 output cols
__global__ __launch_bounds__(256)
void gather_sum(const float* __restrict__ tables, const float* __restrict__ bias,
                const int* __restrict__ code, const float* __restrict__ score,
                float* __restrict__ out)
{
    __shared__ int   sc[NUM_TABLE];
    __shared__ float sw[NUM_TABLE];

    const int n   = blockIdx.x;
    const int tid = threadIdx.x;

    if (tid < NUM_TABLE) {
        sc[tid] = code[n * NUM_TABLE + tid];
        sw[tid] = score[n * NUM_TABLE + tid];
    }
    __syncthreads();

    float4 acc = *(const float4*)&bias[tid * 4];

    #pragma unroll 4
    for (int t = 0; t < NUM_TABLE; ++t) {
        int   c = sc[t];
        float w = sw[t];
        const float* row = tables + ((size_t)(t * TABLE_SZ + c)) * OUTD;
        float4 v = *(const float4*)&row[tid * 4];
        acc.x += v.x * w;
        acc.y += v.y * w;
        acc.z += v.z * w;
        acc.w += v.w * w;
    }

    *(float4*)&out[(size_t)n * OUTD + tid * 4] = acc;
}

extern "C" void kernel_launch(void* const* d_in, const int* in_sizes, int n_in,
                              void* d_out, int out_size, void* d_ws, size_t ws_size,
                              hipStream_t stream) {
    const float* x      = (const float*)d_in[0];  // [B,S,HIDDEN]
    const float* W      = (const float*)d_in[1];  // [HIDDEN, TOTAL_DIM]
    const float* bproj  = (const float*)d_in[2];  // [TOTAL_DIM]
    const float* tables = (const float*)d_in[3];  // [NUM_TABLE*TABLE_SZ, OUTD]
    const float* bias   = (const float*)d_in[4];  // [OUTD]
    float* out = (float*)d_out;

    const int N = in_sizes[0] / HIDDEN;           // 8192

    // workspace layout: z [N*640] f32 | code [N*64] i32 | score [N*64] f32
    char* ws = (char*)d_ws;
    float* z     = (float*)ws;
    int*   code  = (int*)(ws + (size_t)N * TOTAL_DIM * sizeof(float));
    float* score = (float*)(ws + (size_t)N * TOTAL_DIM * sizeof(float)
                               + (size_t)N * NUM_TABLE * sizeof(int));

    dim3 g1(N / BM, TOTAL_DIM / BN);
    gemm_proj<<<g1, 256, 0, stream>>>(x, W, bproj, z);

    int NT = N * NUM_TABLE;
    code_score<<<(NT + 255) / 256, 256, 0, stream>>>(z, code, score, NT);

    gather_sum<<<N, 256, 0, stream>>>(tables, bias, code, score, out);
}

// Round 3
// 376.131 us; speedup vs baseline: 1.2229x; 1.2229x over previous
//
#include <hip/hip_runtime.h>
#include <cstddef>
#include <cstdint>

#define HIDDEN    1024
#define OUTD      1024
#define NUM_TABLE 64
#define CODE_LEN  10
#define TABLE_SZ  1024
#define TOTAL_DIM 640

typedef float  fx4 __attribute__((ext_vector_type(4)));
typedef ushort ux4 __attribute__((ext_vector_type(4)));

// ---------------- GEMM: z = x @ W + b_proj  (fp32, vector ALU) ----------------
// 128x64 tile, BK=16, 256 threads, 8x4 acc per thread.
#define BM 128
#define BN 64
#define BK 16

__global__ __launch_bounds__(256)
void gemm_proj(const float* __restrict__ x, const float* __restrict__ W,
               const float* __restrict__ bproj, float* __restrict__ z)
{
    // As transposed: As[k][m], row stride 132 floats (528 B, 16B-aligned)
    __shared__ float As[BK][BM + 4];
    __shared__ float Bs[BK][BN];

    const int tid  = threadIdx.x;
    const int brow = blockIdx.x * BM;
    const int bcol = blockIdx.y * BN;
    const int tr   = tid >> 4;   // 0..15 -> rows tr*8..tr*8+7
    const int tc   = tid & 15;   // 0..15 -> cols tc*4..tc*4+3

    float acc[8][4] = {};

    for (int k0 = 0; k0 < HIDDEN; k0 += BK) {
        // A tile: 128 rows x 16 k, float4 loads, transposed store (2-way LDS write = free)
        #pragma unroll
        for (int i = 0; i < 2; ++i) {
            int lin = tid + i * 256;
            int r = lin >> 2, c4 = lin & 3;
            float4 a = *(const float4*)&x[(size_t)(brow + r) * HIDDEN + k0 + c4 * 4];
            As[c4 * 4 + 0][r] = a.x;
            As[c4 * 4 + 1][r] = a.y;
            As[c4 * 4 + 2][r] = a.z;
            As[c4 * 4 + 3][r] = a.w;
        }
        // B tile: 16 k x 64 cols, one float4 per thread
        {
            int kk = tid >> 4, m4 = tid & 15;
            *(float4*)&Bs[kk][m4 * 4] =
                *(const float4*)&W[(size_t)(k0 + kk) * TOTAL_DIM + bcol + m4 * 4];
        }
        __syncthreads();

        #pragma unroll
        for (int kk = 0; kk < BK; ++kk) {
            float4 a0 = *(const float4*)&As[kk][tr * 8];
            float4 a1 = *(const float4*)&As[kk][tr * 8 + 4];
            float4 b  = *(const float4*)&Bs[kk][tc * 4];
            float av[8] = {a0.x, a0.y, a0.z, a0.w, a1.x, a1.y, a1.z, a1.w};
            #pragma unroll
            for (int i = 0; i < 8; ++i) {
                acc[i][0] += av[i] * b.x;
                acc[i][1] += av[i] * b.y;
                acc[i][2] += av[i] * b.z;
                acc[i][3] += av[i] * b.w;
            }
        }
        __syncthreads();
    }

    float4 bb = *(const float4*)&bproj[bcol + tc * 4];
    #pragma unroll
    for (int i = 0; i < 8; ++i) {
        int r = brow + tr * 8 + i;
        float4 o = {acc[i][0] + bb.x, acc[i][1] + bb.y, acc[i][2] + bb.z, acc[i][3] + bb.w};
        *(float4*)&z[(size_t)r * TOTAL_DIM + bcol + tc * 4] = o;
    }
}

// ---------------- code / score from z ----------------
__global__ __launch_bounds__(256)
void code_score(const float* __restrict__ z, int* __restrict__ code,
                float* __restrict__ score, int NT)
{
    int idx = blockIdx.x * 256 + threadIdx.x;
    if (idx >= NT) return;
    int n = idx >> 6;        // token
    int t = idx & 63;        // table
    const float* zp = z + (size_t)n * TOTAL_DIM + t * CODE_LEN;
    float s = 1.0f;
    int   c = 0;
    #pragma unroll
    for (int i = 0; i < CODE_LEN; ++i) {
        float v = zp[i];
        s *= 0.5f * (1.0f + tanhf(fabsf(v)));
        c |= (v > 0.0f) ? (1 << i) : 0;
    }
    code[idx]  = c;
    score[idx] = s;
}

// ---------------- fp32 -> bf16 table conversion (RNE), nt loads ----------------
static __device__ __forceinline__ ushort f2bf(float f) {
    uint32_t u = __float_as_uint(f);
    return (ushort)((u + 0x7FFFu + ((u >> 16) & 1u)) >> 16);
}

__global__ __launch_bounds__(256)
void convert_tables(const float* __restrict__ t, ushort* __restrict__ o, int n4)
{
    const fx4* tp = (const fx4*)t;
    int stride = gridDim.x * 256;
    for (int i = blockIdx.x * 256 + threadIdx.x; i < n4; i += stride) {
        fx4 v = __builtin_nontemporal_load(&tp[i]);
        ux4 u;
        u.x = f2bf(v.x); u.y = f2bf(v.y); u.z = f2bf(v.z); u.w = f2bf(v.w);
        *(ux4*)&o[(size_t)i * 4] = u;
    }
}

// ---------------- gather + weighted sum (bf16 tables) ----------------
__global__ __launch_bounds__(256)
void gather_sum_bf16(const ushort* __restrict__ btab, const float* __restrict__ bias,
                     const int* __restrict__ code, const float* __restrict__ score,
                     float* __restrict__ out)
{
    __shared__ int   sc[NUM_TABLE];
    __shared__ float sw[NUM_TABLE];

    const int n   = blockIdx.x;
    const int tid = threadIdx.x;

    if (tid < NUM_TABLE) {
        sc[tid] = code[n * NUM_TABLE + tid];
        sw[tid] = score[n * NUM_TABLE + tid];
    }
    __syncthreads();

    float4 acc = *(const float4*)&bias[tid * 4];

    #pragma unroll 4
    for (int t = 0; t < NUM_TABLE; ++t) {
        const ux4 v = *(const ux4*)&btab[((size_t)(t * TABLE_SZ + sc[t])) * OUTD + tid * 4];
        float w = sw[t];
        acc.x += w * __uint_as_float((uint32_t)v.x << 16);
        acc.y += w * __uint_as_float((uint32_t)v.y << 16);
        acc.z += w * __uint_as_float((uint32_t)v.z << 16);
        acc.w += w * __uint_as_float((uint32_t)v.w << 16);
    }

    *(float4*)&out[(size_t)n * OUTD + tid * 4] = acc;
}

// ---------------- fallback: fp32 gather (if ws can't hold bf16 tables) ----------------
__global__ __launch_bounds__(256)
void gather_sum_f32(const float* __restrict__ tables, const float* __restrict__ bias,
                    const int* __restrict__ code, const float* __restrict__ score,
                    float* __restrict__ out)
{
    __shared__ int   sc[NUM_TABLE];
    __shared__ float sw[NUM_TABLE];

    const int n   = blockIdx.x;
    const int tid = threadIdx.x;

    if (tid < NUM_TABLE) {
        sc[tid] = code[n * NUM_TABLE + tid];
        sw[tid] = score[n * NUM_TABLE + tid];
    }
    __syncthreads();

    float4 acc = *(const float4*)&bias[tid * 4];

    #pragma unroll 4
    for (int t = 0; t < NUM_TABLE; ++t) {
        const float* row = tables + ((size_t)(t * TABLE_SZ + sc[t])) * OUTD;
        float4 v = *(const float4*)&row[tid * 4];
        float w = sw[t];
        acc.x += v.x * w; acc.y += v.y * w; acc.z += v.z * w; acc.w += v.w * w;
    }

    *(float4*)&out[(size_t)n * OUTD + tid * 4] = acc;
}

extern "C" void kernel_launch(void* const* d_in, const int* in_sizes, int n_in,
                              void* d_out, int out_size, void* d_ws, size_t ws_size,
                              hipStream_t stream) {
    const float* x      = (const float*)d_in[0];  // [B,S,HIDDEN]
    const float* W      = (const float*)d_in[1];  // [HIDDEN, TOTAL_DIM]
    const float* bproj  = (const float*)d_in[2];  // [TOTAL_DIM]
    const float* tables = (const float*)d_in[3];  // [NUM_TABLE*TABLE_SZ, OUTD]
    const float* bias   = (const float*)d_in[4];  // [OUTD]
    float* out = (float*)d_out;

    const int N = in_sizes[0] / HIDDEN;           // 8192

    // workspace layout: z [N*640] f32 | code [N*64] i32 | score [N*64] f32 | btab bf16
    char* ws = (char*)d_ws;
    size_t off_z     = 0;
    size_t off_code  = off_z + (size_t)N * TOTAL_DIM * sizeof(float);
    size_t off_score = off_code + (size_t)N * NUM_TABLE * sizeof(int);
    size_t off_btab  = off_score + (size_t)N * NUM_TABLE * sizeof(float);
    size_t tab_elems = (size_t)NUM_TABLE * TABLE_SZ * OUTD;   // 64M
    size_t need      = off_btab + tab_elems * sizeof(ushort);

    float* z     = (float*)(ws + off_z);
    int*   code  = (int*)(ws + off_code);
    float* score = (float*)(ws + off_score);
    ushort* btab = (ushort*)(ws + off_btab);

    dim3 g1(N / BM, TOTAL_DIM / BN);
    gemm_proj<<<g1, 256, 0, stream>>>(x, W, bproj, z);

    int NT = N * NUM_TABLE;
    code_score<<<(NT + 255) / 256, 256, 0, stream>>>(z, code, score, NT);

    if (ws_size >= need) {
        int n4 = (int)(tab_elems / 4);            // 16M float4s
        convert_tables<<<2048, 256, 0, stream>>>(tables, btab, n4);
        gather_sum_bf16<<<N, 256, 0, stream>>>(btab, bias, code, score, out);
    } else {
        gather_sum_f32<<<N, 256, 0, stream>>>(tables, bias, code, score, out);
    }
}

// Round 4
// 366.201 us; speedup vs baseline: 1.2561x; 1.0271x over previous
//
#include <hip/hip_runtime.h>
#include <cstddef>
#include <cstdint>

#define HIDDEN    1024
#define OUTD      1024
#define NUM_TABLE 64
#define CODE_LEN  10
#define TABLE_SZ  1024
#define TOTAL_DIM 640

typedef float  fx4 __attribute__((ext_vector_type(4)));
typedef ushort ux4 __attribute__((ext_vector_type(4)));

// ---------------- GEMM: z = x @ W + b_proj  (fp32, vector ALU) ----------------
// 64x64 tile, BK=32, 256 threads, 4x4 acc/thread. Grid = 128x10 = 1280 blocks
// (5 blocks/CU -> 20 waves/CU; the 128x64 variant gave only 640 blocks = 23% occ).
#define BM 64
#define BN 64
#define BK 32

__global__ __launch_bounds__(256)
void gemm_proj(const float* __restrict__ x, const float* __restrict__ W,
               const float* __restrict__ bproj, float* __restrict__ z)
{
    // As transposed: As[k][m], row stride 68 floats (16B-aligned for float4 reads)
    __shared__ float As[BK][BM + 4];
    __shared__ float Bs[BK][BN];

    const int tid  = threadIdx.x;
    const int brow = blockIdx.x * BM;
    const int bcol = blockIdx.y * BN;
    const int tr   = tid >> 4;   // 0..15 -> rows tr*4..tr*4+3
    const int tc   = tid & 15;   // 0..15 -> cols tc*4..tc*4+3

    float acc[4][4] = {};

    for (int k0 = 0; k0 < HIDDEN; k0 += BK) {
        // A tile: 64 rows x 32 k = 512 float4, 2 per thread; transposed store
        #pragma unroll
        for (int i = 0; i < 2; ++i) {
            int lin = tid + i * 256;
            int r = lin >> 3, c8 = lin & 7;
            float4 a = *(const float4*)&x[(size_t)(brow + r) * HIDDEN + k0 + c8 * 4];
            As[c8 * 4 + 0][r] = a.x;
            As[c8 * 4 + 1][r] = a.y;
            As[c8 * 4 + 2][r] = a.z;
            As[c8 * 4 + 3][r] = a.w;
        }
        // B tile: 32 k x 64 cols = 512 float4, 2 per thread
        #pragma unroll
        for (int i = 0; i < 2; ++i) {
            int lin = tid + i * 256;
            int kk = lin >> 4, m4 = lin & 15;
            *(float4*)&Bs[kk][m4 * 4] =
                *(const float4*)&W[(size_t)(k0 + kk) * TOTAL_DIM + bcol + m4 * 4];
        }
        __syncthreads();

        #pragma unroll
        for (int kk = 0; kk < BK; ++kk) {
            float4 a = *(const float4*)&As[kk][tr * 4];   // broadcast: 4 addrs/wave
            float4 b = *(const float4*)&Bs[kk][tc * 4];   // 16 addrs/wave
            acc[0][0] += a.x * b.x; acc[0][1] += a.x * b.y; acc[0][2] += a.x * b.z; acc[0][3] += a.x * b.w;
            acc[1][0] += a.y * b.x; acc[1][1] += a.y * b.y; acc[1][2] += a.y * b.z; acc[1][3] += a.y * b.w;
            acc[2][0] += a.z * b.x; acc[2][1] += a.z * b.y; acc[2][2] += a.z * b.z; acc[2][3] += a.z * b.w;
            acc[3][0] += a.w * b.x; acc[3][1] += a.w * b.y; acc[3][2] += a.w * b.z; acc[3][3] += a.w * b.w;
        }
        __syncthreads();
    }

    float4 bb = *(const float4*)&bproj[bcol + tc * 4];
    #pragma unroll
    for (int i = 0; i < 4; ++i) {
        int r = brow + tr * 4 + i;
        float4 o = {acc[i][0] + bb.x, acc[i][1] + bb.y, acc[i][2] + bb.z, acc[i][3] + bb.w};
        *(float4*)&z[(size_t)r * TOTAL_DIM + bcol + tc * 4] = o;
    }
}

// ---------------- code / score from z ----------------
__global__ __launch_bounds__(256)
void code_score(const float* __restrict__ z, int* __restrict__ code,
                float* __restrict__ score, int NT)
{
    int idx = blockIdx.x * 256 + threadIdx.x;
    if (idx >= NT) return;
    int n = idx >> 6;        // token
    int t = idx & 63;        // table
    const float* zp = z + (size_t)n * TOTAL_DIM + t * CODE_LEN;
    float s = 1.0f;
    int   c = 0;
    #pragma unroll
    for (int i = 0; i < CODE_LEN; ++i) {
        float v = zp[i];
        s *= 0.5f * (1.0f + tanhf(fabsf(v)));
        c |= (v > 0.0f) ? (1 << i) : 0;
    }
    code[idx]  = c;
    score[idx] = s;
}

// ---------------- fp32 -> bf16 table conversion (RNE), nt loads ----------------
static __device__ __forceinline__ ushort f2bf(float f) {
    uint32_t u = __float_as_uint(f);
    return (ushort)((u + 0x7FFFu + ((u >> 16) & 1u)) >> 16);
}

__global__ __launch_bounds__(256)
void convert_tables(const float* __restrict__ t, ushort* __restrict__ o, int n4)
{
    const fx4* tp = (const fx4*)t;
    int stride = gridDim.x * 256;
    for (int i = blockIdx.x * 256 + threadIdx.x; i < n4; i += stride) {
        fx4 v = __builtin_nontemporal_load(&tp[i]);
        ux4 u;
        u.x = f2bf(v.x); u.y = f2bf(v.y); u.z = f2bf(v.z); u.w = f2bf(v.w);
        *(ux4*)&o[(size_t)i * 4] = u;
    }
}

// ---------------- gather + weighted sum (bf16 tables) ----------------
__global__ __launch_bounds__(256)
void gather_sum_bf16(const ushort* __restrict__ btab, const float* __restrict__ bias,
                     const int* __restrict__ code, const float* __restrict__ score,
                     float* __restrict__ out)
{
    __shared__ int   sc[NUM_TABLE];
    __shared__ float sw[NUM_TABLE];

    const int n   = blockIdx.x;
    const int tid = threadIdx.x;

    if (tid < NUM_TABLE) {
        sc[tid] = code[n * NUM_TABLE + tid];
        sw[tid] = score[n * NUM_TABLE + tid];
    }
    __syncthreads();

    float4 acc = *(const float4*)&bias[tid * 4];

    #pragma unroll 4
    for (int t = 0; t < NUM_TABLE; ++t) {
        const ux4 v = *(const ux4*)&btab[((size_t)(t * TABLE_SZ + sc[t])) * OUTD + tid * 4];
        float w = sw[t];
        acc.x += w * __uint_as_float((uint32_t)v.x << 16);
        acc.y += w * __uint_as_float((uint32_t)v.y << 16);
        acc.z += w * __uint_as_float((uint32_t)v.z << 16);
        acc.w += w * __uint_as_float((uint32_t)v.w << 16);
    }

    *(float4*)&out[(size_t)n * OUTD + tid * 4] = acc;
}

// ---------------- fallback: fp32 gather (if ws can't hold bf16 tables) ----------------
__global__ __launch_bounds__(256)
void gather_sum_f32(const float* __restrict__ tables, const float* __restrict__ bias,
                    const int* __restrict__ code, const float* __restrict__ score,
                    float* __restrict__ out)
{
    __shared__ int   sc[NUM_TABLE];
    __shared__ float sw[NUM_TABLE];

    const int n   = blockIdx.x;
    const int tid = threadIdx.x;

    if (tid < NUM_TABLE) {
        sc[tid] = code[n * NUM_TABLE + tid];
        sw[tid] = score[n * NUM_TABLE + tid];
    }
    __syncthreads();

    float4 acc = *(const float4*)&bias[tid * 4];

    #pragma unroll 4
    for (int t = 0; t < NUM_TABLE; ++t) {
        const float* row = tables + ((size_t)(t * TABLE_SZ + sc[t])) * OUTD;
        float4 v = *(const float4*)&row[tid * 4];
        float w = sw[t];
        acc.x += v.x * w; acc.y += v.y * w; acc.z += v.z * w; acc.w += v.w * w;
    }

    *(float4*)&out[(size_t)n * OUTD + tid * 4] = acc;
}

extern "C" void kernel_launch(void* const* d_in, const int* in_sizes, int n_in,
                              void* d_out, int out_size, void* d_ws, size_t ws_size,
                              hipStream_t stream) {
    const float* x      = (const float*)d_in[0];  // [B,S,HIDDEN]
    const float* W      = (const float*)d_in[1];  // [HIDDEN, TOTAL_DIM]
    const float* bproj  = (const float*)d_in[2];  // [TOTAL_DIM]
    const float* tables = (const float*)d_in[3];  // [NUM_TABLE*TABLE_SZ, OUTD]
    const float* bias   = (const float*)d_in[4];  // [OUTD]
    float* out = (float*)d_out;

    const int N = in_sizes[0] / HIDDEN;           // 8192

    // workspace layout: z [N*640] f32 | code [N*64] i32 | score [N*64] f32 | btab bf16
    char* ws = (char*)d_ws;
    size_t off_z     = 0;
    size_t off_code  = off_z + (size_t)N * TOTAL_DIM * sizeof(float);
    size_t off_score = off_code + (size_t)N * NUM_TABLE * sizeof(int);
    size_t off_btab  = off_score + (size_t)N * NUM_TABLE * sizeof(float);
    size_t tab_elems = (size_t)NUM_TABLE * TABLE_SZ * OUTD;   // 64M
    size_t need      = off_btab + tab_elems * sizeof(ushort);

    float* z     = (float*)(ws + off_z);
    int*   code  = (int*)(ws + off_code);
    float* score = (float*)(ws + off_score);
    ushort* btab = (ushort*)(ws + off_btab);

    dim3 g1(N / BM, TOTAL_DIM / BN);
    gemm_proj<<<g1, 256, 0, stream>>>(x, W, bproj, z);

    int NT = N * NUM_TABLE;
    code_score<<<(NT + 255) / 256, 256, 0, stream>>>(z, code, score, NT);

    if (ws_size >= need) {
        int n4 = (int)(tab_elems / 4);            // 16M float4s
        convert_tables<<<2048, 256, 0, stream>>>(tables, btab, n4);
        gather_sum_bf16<<<N, 256, 0, stream>>>(btab, bias, code, score, out);
    } else {
        gather_sum_f32<<<N, 256, 0, stream>>>(tables, bias, code, score, out);
    }
}

// Round 6
// 344.919 us; speedup vs baseline: 1.3336x; 1.0617x over previous
//
#include <hip/hip_runtime.h>
#include <cstddef>
#include <cstdint>

#define HIDDEN    1024
#define OUTD      1024
#define NUM_TABLE 64
#define CODE_LEN  10
#define TABLE_SZ  1024
#define TOTAL_DIM 640

#define TAU   1e-3f
#define FCAP  65536u

typedef float  fx4    __attribute__((ext_vector_type(4)));
typedef ushort ux4    __attribute__((ext_vector_type(4)));
typedef ushort ux8    __attribute__((ext_vector_type(8)));
typedef short  bf16x8 __attribute__((ext_vector_type(8)));
typedef float  f32x4  __attribute__((ext_vector_type(4)));

// ---------- bf16 helpers (truncation split: v = hi + lo + O(2^-16 v)) ----------
struct bfp { ushort hi, lo; };
static __device__ __forceinline__ bfp split2(float v) {
    uint32_t u  = __float_as_uint(v);
    float    fh = __uint_as_float(u & 0xFFFF0000u);
    uint32_t ul = __float_as_uint(v - fh);   // exact subtraction
    bfp r; r.hi = (ushort)(u >> 16); r.lo = (ushort)(ul >> 16);
    return r;
}
static __device__ __forceinline__ ushort f2bf(float f) {   // RNE, for tables
    uint32_t u = __float_as_uint(f);
    return (ushort)((u + 0x7FFFu + ((u >> 16) & 1u)) >> 16);
}

// ---------------- split + transpose W: [1024][640] f32 -> wht/wlt [640][1024] bf16 ----
__global__ __launch_bounds__(256)
void split_wt(const float* __restrict__ W, ushort* __restrict__ wht, ushort* __restrict__ wlt)
{
    __shared__ float t[32][33];
    const int d0 = blockIdx.x * 32, k0 = blockIdx.y * 32;
    const int lx = threadIdx.x & 31, ly = threadIdx.x >> 5;   // 32 x 8
    #pragma unroll
    for (int i = 0; i < 32; i += 8)
        t[ly + i][lx] = W[(size_t)(k0 + ly + i) * TOTAL_DIM + d0 + lx];
    __syncthreads();
    #pragma unroll
    for (int i = 0; i < 32; i += 8) {
        bfp s = split2(t[lx][ly + i]);        // = W[k0+lx][d0+ly+i]
        size_t o = (size_t)(d0 + ly + i) * HIDDEN + k0 + lx;
        wht[o] = s.hi; wlt[o] = s.lo;
    }
}

// ---------------- MFMA GEMM: z = x @ W + b  via bf16x3 ----------------
// x [N,1024] fp32 (split in-register), W^T h/l [640][1024] bf16.
// 128x128 tile, BK=32, 4 waves (2x2), each wave 4x4 frags of 16x16x32.
#define GBM 128
#define GBN 128
#define GBK 32
#define LDK 40   // padded inner dim (80 B row stride: 16B-aligned, ~2-way banks)

__global__ __launch_bounds__(256)
void gemm_mfma(const float* __restrict__ x, const ushort* __restrict__ wht,
               const ushort* __restrict__ wlt, const float* __restrict__ bproj,
               float* __restrict__ z)
{
    __shared__ ushort Ah[GBM][LDK];
    __shared__ ushort Al[GBM][LDK];
    __shared__ ushort Bh[GBN][LDK];
    __shared__ ushort Bl[GBN][LDK];

    const int tid  = threadIdx.x;
    const int lane = tid & 63, wid = tid >> 6;
    const int wr = wid >> 1, wc = wid & 1;           // 2x2 wave grid
    const int brow = blockIdx.x * GBM;
    const int bcol = blockIdx.y * GBN;
    const int fr = lane & 15, fq = lane >> 4;

    f32x4 acc[4][4] = {};

    for (int k0 = 0; k0 < HIDDEN; k0 += GBK) {
        // stage A: 128x32 fp32, split in-register -> Ah/Al
        #pragma unroll
        for (int i = 0; i < 4; ++i) {
            int c = tid + i * 256;                   // 0..1023
            int r = c >> 3, kc = (c & 7) * 4;
            fx4 v = *(const fx4*)&x[(size_t)(brow + r) * HIDDEN + k0 + kc];
            bfp s0 = split2(v.x), s1 = split2(v.y), s2 = split2(v.z), s3 = split2(v.w);
            ux4 h, l;
            h.x = s0.hi; l.x = s0.lo;
            h.y = s1.hi; l.y = s1.lo;
            h.z = s2.hi; l.z = s2.lo;
            h.w = s3.hi; l.w = s3.lo;
            *(ux4*)&Ah[r][kc] = h;
            *(ux4*)&Al[r][kc] = l;
        }
        // stage B^T tiles: 128n x 32k bf16 each
        #pragma unroll
        for (int i = 0; i < 2; ++i) {
            int c = tid + i * 256;                   // 0..511
            int nr = c >> 2, kc = (c & 3) * 8;
            size_t o = (size_t)(bcol + nr) * HIDDEN + k0 + kc;
            *(ux8*)&Bh[nr][kc] = *(const ux8*)&wht[o];
            *(ux8*)&Bl[nr][kc] = *(const ux8*)&wlt[o];
        }
        __syncthreads();

        bf16x8 ah[4], al[4], bh[4], bl[4];
        #pragma unroll
        for (int m = 0; m < 4; ++m) {
            ah[m] = *(const bf16x8*)&Ah[wr * 64 + m * 16 + fr][fq * 8];
            al[m] = *(const bf16x8*)&Al[wr * 64 + m * 16 + fr][fq * 8];
        }
        #pragma unroll
        for (int n = 0; n < 4; ++n) {
            bh[n] = *(const bf16x8*)&Bh[wc * 64 + n * 16 + fr][fq * 8];
            bl[n] = *(const bf16x8*)&Bl[wc * 64 + n * 16 + fr][fq * 8];
        }
        #pragma unroll
        for (int m = 0; m < 4; ++m)
            #pragma unroll
            for (int n = 0; n < 4; ++n) {
                acc[m][n] = __builtin_amdgcn_mfma_f32_16x16x32_bf16(ah[m], bh[n], acc[m][n], 0, 0, 0);
                acc[m][n] = __builtin_amdgcn_mfma_f32_16x16x32_bf16(ah[m], bl[n], acc[m][n], 0, 0, 0);
                acc[m][n] = __builtin_amdgcn_mfma_f32_16x16x32_bf16(al[m], bh[n], acc[m][n], 0, 0, 0);
            }
        __syncthreads();
    }

    // epilogue: C/D mapping col=lane&15, row=(lane>>4)*4+reg  [m89]
    #pragma unroll
    for (int n = 0; n < 4; ++n) {
        int col = bcol + wc * 64 + n * 16 + fr;
        float bb = bproj[col];
        #pragma unroll
        for (int m = 0; m < 4; ++m) {
            int rbase = brow + wr * 64 + m * 16 + fq * 4;
            #pragma unroll
            for (int j = 0; j < 4; ++j)
                z[(size_t)(rbase + j) * TOTAL_DIM + col] = acc[m][n][j] + bb;
        }
    }
}

// ---------------- code / score + near-zero flagging ----------------
__global__ __launch_bounds__(256)
void code_score2(const float* __restrict__ z, int* __restrict__ code,
                 float* __restrict__ score, uint32_t* __restrict__ flags,
                 uint32_t* __restrict__ cnt, int NT)
{
    int idx = blockIdx.x * 256 + threadIdx.x;
    if (idx >= NT) return;
    int n = idx >> 6;
    int t = idx & 63;
    const float* zp = z + (size_t)n * TOTAL_DIM + t * CODE_LEN;
    float s = 1.0f;
    int   c = 0;
    #pragma unroll
    for (int i = 0; i < CODE_LEN; ++i) {
        float v = zp[i];
        if (fabsf(v) < TAU) {                       // sign uncertain under bf16x3
            uint32_t slot = atomicAdd(cnt, 1u);
            if (slot < FCAP) flags[slot] = (uint32_t)(n * TOTAL_DIM + t * CODE_LEN + i);
        }
        s *= 0.5f * (1.0f + tanhf(fabsf(v)));
        c |= (v > 0.0f) ? (1 << i) : 0;
    }
    code[idx]  = c;
    score[idx] = s;
}

// ---------------- exact fp32 recompute of flagged z; fix code bits ----------------
__global__ __launch_bounds__(256)
void fixz(const float* __restrict__ x, const float* __restrict__ W,
          const float* __restrict__ bproj, const float* __restrict__ z,
          int* __restrict__ code, const uint32_t* __restrict__ flags,
          const uint32_t* __restrict__ cnt)
{
    const int lane = threadIdx.x & 63;
    const int gw   = (blockIdx.x * 256 + threadIdx.x) >> 6;
    const int nw   = (gridDim.x * 256) >> 6;
    uint32_t count = *cnt;
    if (count > FCAP) count = FCAP;

    for (uint32_t f = gw; f < count; f += nw) {
        uint32_t e = flags[f];
        int n = e / TOTAL_DIM, d = e % TOTAL_DIM;
        const float* xr = x + (size_t)n * HIDDEN;
        float p = 0.0f;
        #pragma unroll
        for (int j = 0; j < 16; ++j) {
            int k = lane + j * 64;
            p = fmaf(xr[k], W[(size_t)k * TOTAL_DIM + d], p);
        }
        #pragma unroll
        for (int off = 32; off; off >>= 1) p += __shfl_xor(p, off);
        float v = p + bproj[d];
        if (lane == 0) {
            float vold = z[e];
            if ((v > 0.0f) != (vold > 0.0f)) {
                int t = d / CODE_LEN, i = d % CODE_LEN;
                atomicXor(&code[n * NUM_TABLE + t], 1 << i);
            }
        }
    }
}

// ---------------- fp32 -> bf16 table conversion (RNE), nt loads ----------------
__global__ __launch_bounds__(256)
void convert_tables(const float* __restrict__ t, ushort* __restrict__ o, int n4)
{
    const fx4* tp = (const fx4*)t;
    int stride = gridDim.x * 256;
    for (int i = blockIdx.x * 256 + threadIdx.x; i < n4; i += stride) {
        fx4 v = __builtin_nontemporal_load(&tp[i]);
        ux4 u;
        u.x = f2bf(v.x); u.y = f2bf(v.y); u.z = f2bf(v.z); u.w = f2bf(v.w);
        *(ux4*)&o[(size_t)i * 4] = u;
    }
}

// ---------------- gather + weighted sum (bf16 tables) ----------------
__global__ __launch_bounds__(256)
void gather_sum_bf16(const ushort* __restrict__ btab, const float* __restrict__ bias,
                     const int* __restrict__ code, const float* __restrict__ score,
                     float* __restrict__ out)
{
    __shared__ int   sc[NUM_TABLE];
    __shared__ float sw[NUM_TABLE];

    const int n   = blockIdx.x;
    const int tid = threadIdx.x;

    if (tid < NUM_TABLE) {
        sc[tid] = code[n * NUM_TABLE + tid];
        sw[tid] = score[n * NUM_TABLE + tid];
    }
    __syncthreads();

    float4 acc = *(const float4*)&bias[tid * 4];

    #pragma unroll 4
    for (int t = 0; t < NUM_TABLE; ++t) {
        const ux4 v = *(const ux4*)&btab[((size_t)(t * TABLE_SZ + sc[t])) * OUTD + tid * 4];
        float w = sw[t];
        acc.x += w * __uint_as_float((uint32_t)v.x << 16);
        acc.y += w * __uint_as_float((uint32_t)v.y << 16);
        acc.z += w * __uint_as_float((uint32_t)v.z << 16);
        acc.w += w * __uint_as_float((uint32_t)v.w << 16);
    }

    *(float4*)&out[(size_t)n * OUTD + tid * 4] = acc;
}

// ---------------- fallback path (ws too small): fp32 vector GEMM + f32 gather ----
#define BM 64
#define BN 64
#define BK 32
__global__ __launch_bounds__(256)
void gemm_proj(const float* __restrict__ x, const float* __restrict__ W,
               const float* __restrict__ bproj, float* __restrict__ z)
{
    __shared__ float As[BK][BM + 4];
    __shared__ float Bs[BK][BN];
    const int tid  = threadIdx.x;
    const int brow = blockIdx.x * BM;
    const int bcol = blockIdx.y * BN;
    const int tr   = tid >> 4;
    const int tc   = tid & 15;
    float acc[4][4] = {};
    for (int k0 = 0; k0 < HIDDEN; k0 += BK) {
        #pragma unroll
        for (int i = 0; i < 2; ++i) {
            int lin = tid + i * 256;
            int r = lin >> 3, c8 = lin & 7;
            float4 a = *(const float4*)&x[(size_t)(brow + r) * HIDDEN + k0 + c8 * 4];
            As[c8 * 4 + 0][r] = a.x; As[c8 * 4 + 1][r] = a.y;
            As[c8 * 4 + 2][r] = a.z; As[c8 * 4 + 3][r] = a.w;
        }
        #pragma unroll
        for (int i = 0; i < 2; ++i) {
            int lin = tid + i * 256;
            int kk = lin >> 4, m4 = lin & 15;
            *(float4*)&Bs[kk][m4 * 4] =
                *(const float4*)&W[(size_t)(k0 + kk) * TOTAL_DIM + bcol + m4 * 4];
        }
        __syncthreads();
        #pragma unroll
        for (int kk = 0; kk < BK; ++kk) {
            float4 a = *(const float4*)&As[kk][tr * 4];
            float4 b = *(const float4*)&Bs[kk][tc * 4];
            acc[0][0] += a.x * b.x; acc[0][1] += a.x * b.y; acc[0][2] += a.x * b.z; acc[0][3] += a.x * b.w;
            acc[1][0] += a.y * b.x; acc[1][1] += a.y * b.y; acc[1][2] += a.y * b.z; acc[1][3] += a.y * b.w;
            acc[2][0] += a.z * b.x; acc[2][1] += a.z * b.y; acc[2][2] += a.z * b.z; acc[2][3] += a.z * b.w;
            acc[3][0] += a.w * b.x; acc[3][1] += a.w * b.y; acc[3][2] += a.w * b.z; acc[3][3] += a.w * b.w;
        }
        __syncthreads();
    }
    float4 bb = *(const float4*)&bproj[bcol + tc * 4];
    #pragma unroll
    for (int i = 0; i < 4; ++i) {
        int r = brow + tr * 4 + i;
        float4 o = {acc[i][0] + bb.x, acc[i][1] + bb.y, acc[i][2] + bb.z, acc[i][3] + bb.w};
        *(float4*)&z[(size_t)r * TOTAL_DIM + bcol + tc * 4] = o;
    }
}

__global__ __launch_bounds__(256)
void code_score(const float* __restrict__ z, int* __restrict__ code,
                float* __restrict__ score, int NT)
{
    int idx = blockIdx.x * 256 + threadIdx.x;
    if (idx >= NT) return;
    int n = idx >> 6, t = idx & 63;
    const float* zp = z + (size_t)n * TOTAL_DIM + t * CODE_LEN;
    float s = 1.0f; int c = 0;
    #pragma unroll
    for (int i = 0; i < CODE_LEN; ++i) {
        float v = zp[i];
        s *= 0.5f * (1.0f + tanhf(fabsf(v)));
        c |= (v > 0.0f) ? (1 << i) : 0;
    }
    code[idx] = c; score[idx] = s;
}

__global__ __launch_bounds__(256)
void gather_sum_f32(const float* __restrict__ tables, const float* __restrict__ bias,
                    const int* __restrict__ code, const float* __restrict__ score,
                    float* __restrict__ out)
{
    __shared__ int   sc[NUM_TABLE];
    __shared__ float sw[NUM_TABLE];
    const int n = blockIdx.x, tid = threadIdx.x;
    if (tid < NUM_TABLE) {
        sc[tid] = code[n * NUM_TABLE + tid];
        sw[tid] = score[n * NUM_TABLE + tid];
    }
    __syncthreads();
    float4 acc = *(const float4*)&bias[tid * 4];
    #pragma unroll 4
    for (int t = 0; t < NUM_TABLE; ++t) {
        const float* row = tables + ((size_t)(t * TABLE_SZ + sc[t])) * OUTD;
        float4 v = *(const float4*)&row[tid * 4];
        float w = sw[t];
        acc.x += v.x * w; acc.y += v.y * w; acc.z += v.z * w; acc.w += v.w * w;
    }
    *(float4*)&out[(size_t)n * OUTD + tid * 4] = acc;
}

extern "C" void kernel_launch(void* const* d_in, const int* in_sizes, int n_in,
                              void* d_out, int out_size, void* d_ws, size_t ws_size,
                              hipStream_t stream) {
    const float* x      = (const float*)d_in[0];
    const float* W      = (const float*)d_in[1];
    const float* bproj  = (const float*)d_in[2];
    const float* tables = (const float*)d_in[3];
    const float* bias   = (const float*)d_in[4];
    float* out = (float*)d_out;

    const int N = in_sizes[0] / HIDDEN;           // 8192

    // ws: z | code | score | btab(128MB; transient sub-allocs: flags,cnt,wht,wlt)
    char* ws = (char*)d_ws;
    size_t off_z     = 0;
    size_t off_code  = off_z + (size_t)N * TOTAL_DIM * sizeof(float);
    size_t off_score = off_code + (size_t)N * NUM_TABLE * sizeof(int);
    size_t off_btab  = off_score + (size_t)N * NUM_TABLE * sizeof(float);
    size_t tab_elems = (size_t)NUM_TABLE * TABLE_SZ * OUTD;
    size_t need      = off_btab + tab_elems * sizeof(ushort);

    float*  z     = (float*)(ws + off_z);
    int*    code  = (int*)(ws + off_code);
    float*  score = (float*)(ws + off_score);
    ushort* btab  = (ushort*)(ws + off_btab);
    // transient (dead before convert_tables writes btab):
    uint32_t* flags = (uint32_t*)(ws + off_btab);                        // 256 KB
    uint32_t* cnt   = (uint32_t*)(ws + off_btab + (size_t)FCAP * 4);     // 4 B
    ushort*   wht   = (ushort*)(ws + off_btab + (1u << 20));             // 1.31 MB
    ushort*   wlt   = (ushort*)(ws + off_btab + (3u << 20));             // 1.31 MB

    int NT = N * NUM_TABLE;

    if (ws_size >= need) {
        dim3 gw(TOTAL_DIM / 32, HIDDEN / 32);
        split_wt<<<gw, 256, 0, stream>>>(W, wht, wlt);

        dim3 g1(N / GBM, TOTAL_DIM / GBN);
        gemm_mfma<<<g1, 256, 0, stream>>>(x, wht, wlt, bproj, z);

        (void)hipMemsetAsync(cnt, 0, 4, stream);
        code_score2<<<(NT + 255) / 256, 256, 0, stream>>>(z, code, score, flags, cnt, NT);
        fixz<<<512, 256, 0, stream>>>(x, W, bproj, z, code, flags, cnt);

        convert_tables<<<2048, 256, 0, stream>>>(tables, btab, (int)(tab_elems / 4));
        gather_sum_bf16<<<N, 256, 0, stream>>>(btab, bias, code, score, out);
    } else {
        dim3 g1(N / BM, TOTAL_DIM / BN);
        gemm_proj<<<g1, 256, 0, stream>>>(x, W, bproj, z);
        code_score<<<(NT + 255) / 256, 256, 0, stream>>>(z, code, score, NT);
        gather_sum_f32<<<N, 256, 0, stream>>>(tables, bias, code, score, out);
    }
}